// Round 6
// baseline (5555.776 us; speedup 1.0000x reference)
//
#include <hip/hip_runtime.h>

// ---------------------------------------------------------------------------
// multiStepModel: LSTM encoder (T=365) -> relu -> constant-input LSTM decoder
// (90 steps) -> relu -> FC.  Persistent cooperative kernel, 1 WG/CU.
// R6: minimal critical path.  B-operand (h) loaded DIRECTLY from LLC into
// MFMA fragment registers (agent-scope atomics, R4-proven coherence); gate
// rows reordered (unit*4+gate) so each lane's 4 accumulator regs are i,f,g,o
// of one (unit,batch) -> LSTM cell entirely in registers (no g_lds round
// trip); pb (covproj+b1 / proj2) register-resident.  2 syncthreads/step.
// Split-f16 3-term MFMA (R5-proven, fp32-class accuracy).
// ---------------------------------------------------------------------------

namespace {
constexpr int B = 128, T = 365, IN = 64, COV = 256, H = 512, OUTL = 90;
constexpr int GB = 4;            // batch groups (independent barrier quorums)
constexpr int GJ = 64;           // hidden groups
constexpr int NWG = GB * GJ;     // 256 workgroups, 1/CU
constexpr int NT = 256;          // threads per WG (4 waves)
constexpr int BS = B / GB;       // 32 batch rows per WG
constexpr int HU = H / GJ;       // 8 hidden units per WG
constexpr int NR = 4 * HU;       // 32 gate rows per WG
constexpr int NSLOT_H = 64;      // 512/8 16B slots (h part of K)
constexpr int NSLOT = 72;        // + 64/8 slots (x part)
}

using ull = unsigned long long;
typedef __attribute__((ext_vector_type(8))) short short8;
typedef __attribute__((ext_vector_type(8))) _Float16 half8;
typedef __attribute__((ext_vector_type(4))) float f32x4;

__device__ unsigned int g_h[2][B][H];      // packed f16 (hi<<16|lo) hidden state
__device__ float g_part[OUTL][GJ][B];      // per-hidden-group FC partials
__device__ int   g_flag[GB][64];           // per-WG monotonic barrier flags

__device__ __forceinline__ float sigf(float x) { return 1.0f / (1.0f + expf(-x)); }

__device__ __forceinline__ float4 fma4(float4 a, float4 b, float4 c) {
  c.x = fmaf(a.x, b.x, c.x); c.y = fmaf(a.y, b.y, c.y);
  c.z = fmaf(a.z, b.z, c.z); c.w = fmaf(a.w, b.w, c.w);
  return c;
}
__device__ __forceinline__ float hsum4(float4 a) { return (a.x + a.y) + (a.z + a.w); }

__device__ __forceinline__ unsigned int pack_split(float v) {
  _Float16 hi = (_Float16)v;
  _Float16 lo = (_Float16)(v - (float)hi);
  return ((unsigned int)__builtin_bit_cast(unsigned short, hi) << 16) |
         (unsigned int)__builtin_bit_cast(unsigned short, lo);
}
__device__ __forceinline__ float unpack_split(unsigned int u) {
  _Float16 hi = __builtin_bit_cast(_Float16, (unsigned short)(u >> 16));
  _Float16 lo = __builtin_bit_cast(_Float16, (unsigned short)(u & 0xFFFFu));
  return (float)hi + (float)lo;
}

__global__ void __launch_bounds__(256) k_init() {
  int t = threadIdx.x;
  if (t < GB * 64) g_flag[t >> 6][t & 63] = 0;
}

__global__ void __launch_bounds__(NT, 1) k_lstm(
    const float* __restrict__ input, const float* __restrict__ covar,
    const float* __restrict__ W_ih1, const float* __restrict__ W_hh1,
    const float* __restrict__ b1,    const float* __restrict__ W_ih2,
    const float* __restrict__ W_hh2, const float* __restrict__ b2,
    const float* __restrict__ W_fc) {
  // W tiles only (B-operand never touches LDS).  Row r = unit*4 + gate
  // (gate order i,f,g,o).  Slot s of row r stored at s ^ (r&7) (XOR swizzle).
  __shared__ __align__(16) short wH[NR][NSLOT * 8];   // 36.9 KB
  __shared__ __align__(16) short wL[NR][NSLOT * 8];   // 36.9 KB
  __shared__ float pb_lds[NR][33];                    // covproj+b1 / proj2
  __shared__ float aux[4][16];                        // decoder FC combine

  const int tid = threadIdx.x;
  const int gb  = blockIdx.x & (GB - 1);
  const int gj  = blockIdx.x >> 2;
  const int bg0 = gb * BS;
  const int j0  = gj * HU;

  const int lane  = tid & 63;
  const int wv    = tid >> 6;
  const int rows0 = (wv >> 1) * 16;        // D row-tile (gate rows)
  const int cols0 = (wv & 1) * 16;         // D col-tile (batch)
  const int ra    = rows0 + (lane & 15);   // A row (reordered gate row)
  const int b_l   = cols0 + (lane & 15);   // B col == D col == batch row
  const int cc    = lane >> 4;             // k-chunk 0..3
  const int x7    = lane & 7;              // XOR swizzle key (== ra&7)
  const int u_l   = (wv >> 1) * 4 + (lane >> 4);  // this lane's unit 0..7

  const int bt = tid & 15;                 // fp32 helper (covproj/proj2)
  const int rt = tid >> 4;

  int nbar = 0;

  // ---- per-gb-group barrier (R4-proven: syncthreads drains vmcnt, flag
  // publish via per-WG atomicExch, 64-lane poll; no fences needed).
  auto gbar = [&](int nb) {
    __syncthreads();
    if (tid == 0) atomicExch(&g_flag[gb][gj], nb);
    if (tid < 64) {
      while (__hip_atomic_load(&g_flag[gb][tid], __ATOMIC_RELAXED,
                               __HIP_MEMORY_SCOPE_AGENT) < nb)
        __builtin_amdgcn_s_sleep(1);
    }
    __syncthreads();
  };

  // ---- split one 8-float slot into f16 hi/lo LDS tiles (XOR-swizzled) ----
  auto put_slot = [&](int r, int s, const float* src) {
    float4 p0 = ((const float4*)src)[0], p1 = ((const float4*)src)[1];
    float f[8] = {p0.x, p0.y, p0.z, p0.w, p1.x, p1.y, p1.z, p1.w};
    short8 hi, lo;
#pragma unroll
    for (int j = 0; j < 8; ++j) {
      _Float16 h_ = (_Float16)f[j];
      _Float16 l_ = (_Float16)(f[j] - (float)h_);
      hi[j] = __builtin_bit_cast(short, h_);
      lo[j] = __builtin_bit_cast(short, l_);
    }
    const int s2 = s ^ (r & 7);
    *(short8*)&wH[r][s2 * 8] = hi;
    *(short8*)&wL[r][s2 * 8] = lo;
  };

  // local row r (0..31): unit = r>>2, gate = r&3  ->  global W row:
  auto wrow = [&](int r) { return (r & 3) * H + j0 + (r >> 2); };

  auto stage_w_hh = [&](const float* Whh) {
    for (int idx = tid; idx < NR * NSLOT_H; idx += NT) {
      const int r = idx >> 6, s = idx & 63;
      put_slot(r, s, Whh + (size_t)wrow(r) * H + s * 8);
    }
  };

  // ======================= one-time setup =======================
  stage_w_hh(W_hh1);
  for (int idx = tid; idx < NR * 8; idx += NT) {   // x cols of W_ih1
    const int r = idx >> 3, s = NSLOT_H + (idx & 7);
    put_slot(r, s, W_ih1 + (size_t)wrow(r) * (IN + COV) + (idx & 7) * 8);
  }
  {  // covariate projection + b1 -> pb_lds (fp32, once)
    const int r0 = rt, r1 = rt + 16;
    const int row0 = wrow(r0), row1 = wrow(r1);
    const float4* c0 = (const float4*)(covar + (size_t)(bg0 + bt) * COV);
    const float4* c1 = (const float4*)(covar + (size_t)(bg0 + bt + 16) * COV);
    const float4* w0 = (const float4*)(W_ih1 + (size_t)row0 * (IN + COV) + IN);
    const float4* w1 = (const float4*)(W_ih1 + (size_t)row1 * (IN + COV) + IN);
    float4 a00 = {0, 0, 0, 0}, a01 = a00, a10 = a00, a11 = a00;
    for (int k = 0; k < COV / 4; ++k) {
      float4 va = c0[k], vb = c1[k], wa = w0[k], wb = w1[k];
      a00 = fma4(va, wa, a00); a01 = fma4(va, wb, a01);
      a10 = fma4(vb, wa, a10); a11 = fma4(vb, wb, a11);
    }
    pb_lds[r0][bt]      = hsum4(a00) + b1[row0];
    pb_lds[r1][bt]      = hsum4(a01) + b1[row1];
    pb_lds[r0][bt + 16] = hsum4(a10) + b1[row0];
    pb_lds[r1][bt + 16] = hsum4(a11) + b1[row1];
  }
  __syncthreads();   // wH/wL + pb_lds ready

  // pb for this lane's (unit, batch): rows rows0 + (lane>>4)*4 + q
  float pb4[4];
#pragma unroll
  for (int q = 0; q < 4; ++q) pb4[q] = pb_lds[rows0 + (lane >> 4) * 4 + q][b_l];

  float c_state = 0.0f;

  // W fragment read (A operand), kbi in [0,18)
  auto rd_w = [&](int kbi, half8& ah, half8& al) {
    const int s2 = (kbi * 4 + cc) ^ x7;
    ah = __builtin_bit_cast(half8, *(const short8*)&wH[ra][s2 * 8]);
    al = __builtin_bit_cast(half8, *(const short8*)&wL[ra][s2 * 8]);
  };

  // register cell: acc[q] + pb4[q] are the i,f,g,o pre-activations
  auto cellp = [&](const f32x4& acc) -> float {
    const float gi = acc[0] + pb4[0];
    const float gf = acc[1] + pb4[1];
    const float gg = acc[2] + pb4[2];
    const float go = acc[3] + pb4[3];
    c_state = sigf(gf) * c_state + sigf(gi) * tanhf(gg);
    return sigf(go) * tanhf(c_state);
  };

  // =================== encoder: 365 steps ===================
  for (int t = 0; t < T; ++t) {
    // x B-frags: direct cached global loads (issued first, consumed first)
    const float* xbase = input + ((size_t)(bg0 + b_l) * T + t) * IN + cc * 8;
    const float4 xa0 = *(const float4*)(xbase + 0);
    const float4 xa1 = *(const float4*)(xbase + 4);
    const float4 xb0 = *(const float4*)(xbase + 32);
    const float4 xb1 = *(const float4*)(xbase + 36);
    // h B-frags: all 64 LLC loads issued up front (pipelined, in-order)
    ull hq[64];
    if (t > 0) {
      const ull* hb = (const ull*)&g_h[t & 1][bg0 + b_l][0];
#pragma unroll
      for (int kb = 0; kb < 16; ++kb)
#pragma unroll
        for (int q = 0; q < 4; ++q)
          hq[kb * 4 + q] = __hip_atomic_load(hb + kb * 16 + cc * 4 + q,
                                             __ATOMIC_RELAXED,
                                             __HIP_MEMORY_SCOPE_AGENT);
    }
    f32x4 aA = {0.f, 0.f, 0.f, 0.f}, aB = aA, aC = aA;
    // ---- x part (W k-blocks 16,17) ----
#pragma unroll
    for (int xc = 0; xc < 2; ++xc) {
      const float4 p0 = xc ? xb0 : xa0, p1 = xc ? xb1 : xa1;
      const float f[8] = {p0.x, p0.y, p0.z, p0.w, p1.x, p1.y, p1.z, p1.w};
      half8 bh, bo;
#pragma unroll
      for (int j = 0; j < 8; ++j) {
        _Float16 h_ = (_Float16)f[j];
        bh[j] = h_;
        bo[j] = (_Float16)(f[j] - (float)h_);
      }
      half8 ah, al;
      rd_w(16 + xc, ah, al);
      aA = __builtin_amdgcn_mfma_f32_16x16x32_f16(ah, bh, aA, 0, 0, 0);
      aB = __builtin_amdgcn_mfma_f32_16x16x32_f16(ah, bo, aB, 0, 0, 0);
      aC = __builtin_amdgcn_mfma_f32_16x16x32_f16(al, bh, aC, 0, 0, 0);
    }
    // ---- h part (W k-blocks 0..15) ----
    if (t > 0) {
#pragma unroll
      for (int kb = 0; kb < 16; ++kb) {
        half8 bh, bo;
#pragma unroll
        for (int q = 0; q < 4; ++q) {
          const ull v = hq[kb * 4 + q];
          const unsigned int u0 = (unsigned int)v;
          const unsigned int u1 = (unsigned int)(v >> 32);
          bh[2 * q]     = __builtin_bit_cast(_Float16, (unsigned short)(u0 >> 16));
          bo[2 * q]     = __builtin_bit_cast(_Float16, (unsigned short)(u0 & 0xFFFFu));
          bh[2 * q + 1] = __builtin_bit_cast(_Float16, (unsigned short)(u1 >> 16));
          bo[2 * q + 1] = __builtin_bit_cast(_Float16, (unsigned short)(u1 & 0xFFFFu));
        }
        half8 ah, al;
        rd_w(kb, ah, al);
        aA = __builtin_amdgcn_mfma_f32_16x16x32_f16(ah, bh, aA, 0, 0, 0);
        aB = __builtin_amdgcn_mfma_f32_16x16x32_f16(ah, bo, aB, 0, 0, 0);
        aC = __builtin_amdgcn_mfma_f32_16x16x32_f16(al, bh, aC, 0, 0, 0);
      }
    }
    f32x4 acc;
#pragma unroll
    for (int q = 0; q < 4; ++q) acc[q] = aA[q] + aB[q] + aC[q];
    float hv = cellp(acc);
    if (t == T - 1) hv = fmaxf(hv, 0.0f);          // relu(h_enc)
    __hip_atomic_store(&g_h[(t + 1) & 1][bg0 + b_l][j0 + u_l], pack_split(hv),
                       __ATOMIC_RELAXED, __HIP_MEMORY_SCOPE_AGENT);
    gbar(++nbar);
  }

  // ====== transition: proj2 = [relu(h_enc),covar] @ W_ih2^T + b2 (fp32) ======
  {
    const int b0 = bt, b1v = bt + 16;
    const int r0 = rt, r1 = rt + 16;
    const int row0 = wrow(r0), row1 = wrow(r1);
    const float* w0 = W_ih2 + (size_t)row0 * (H + COV);
    const float* w1 = W_ih2 + (size_t)row1 * (H + COV);
    const ull* h0 = (const ull*)&g_h[1][bg0 + b0][0];
    const ull* h1 = (const ull*)&g_h[1][bg0 + b1v][0];
    float a00 = 0.f, a01 = 0.f, a10 = 0.f, a11 = 0.f;
    for (int m = 0; m < H / 2; ++m) {   // h part from packed LLC state
      const ull v0 = __hip_atomic_load(h0 + m, __ATOMIC_RELAXED,
                                       __HIP_MEMORY_SCOPE_AGENT);
      const ull v1 = __hip_atomic_load(h1 + m, __ATOMIC_RELAXED,
                                       __HIP_MEMORY_SCOPE_AGENT);
      const float h00 = unpack_split((unsigned int)v0);
      const float h01 = unpack_split((unsigned int)(v0 >> 32));
      const float h10 = unpack_split((unsigned int)v1);
      const float h11 = unpack_split((unsigned int)(v1 >> 32));
      const float wa0 = w0[2 * m], wa1 = w0[2 * m + 1];
      const float wb0 = w1[2 * m], wb1 = w1[2 * m + 1];
      a00 += h00 * wa0 + h01 * wa1;  a01 += h00 * wb0 + h01 * wb1;
      a10 += h10 * wa0 + h11 * wa1;  a11 += h10 * wb0 + h11 * wb1;
    }
    {  // covar part (fp32, cache-hot)
      const float4* c0 = (const float4*)(covar + (size_t)(bg0 + b0) * COV);
      const float4* c1 = (const float4*)(covar + (size_t)(bg0 + b1v) * COV);
      const float4* W0 = (const float4*)w0;
      const float4* W1 = (const float4*)w1;
      float4 s00 = {0, 0, 0, 0}, s01 = s00, s10 = s00, s11 = s00;
      for (int k = 0; k < COV / 4; ++k) {
        float4 ha = c0[k], hb = c1[k], wa = W0[H / 4 + k], wb = W1[H / 4 + k];
        s00 = fma4(ha, wa, s00); s01 = fma4(ha, wb, s01);
        s10 = fma4(hb, wa, s10); s11 = fma4(hb, wb, s11);
      }
      a00 += hsum4(s00); a01 += hsum4(s01);
      a10 += hsum4(s10); a11 += hsum4(s11);
    }
    pb_lds[r0][b0]  = a00 + b2[row0];
    pb_lds[r1][b0]  = a01 + b2[row1];
    pb_lds[r0][b1v] = a10 + b2[row0];
    pb_lds[r1][b1v] = a11 + b2[row1];
  }
  stage_w_hh(W_hh2);        // decoder recurrent weights over encoder ones
  c_state = 0.0f;
  gbar(++nbar);             // orders: h_enc reads done; wH/pb_lds published

#pragma unroll
  for (int q = 0; q < 4; ++q) pb4[q] = pb_lds[rows0 + (lane >> 4) * 4 + q][b_l];
  const float wfc = W_fc[j0 + u_l];

  // =================== decoder: 90 steps ===================
  for (int ot = 0; ot < OUTL; ++ot) {
    f32x4 aA = {0.f, 0.f, 0.f, 0.f}, aB = aA, aC = aA;
    if (ot > 0) {
      ull hq[64];
      const ull* hb = (const ull*)&g_h[ot & 1][bg0 + b_l][0];
#pragma unroll
      for (int kb = 0; kb < 16; ++kb)
#pragma unroll
        for (int q = 0; q < 4; ++q)
          hq[kb * 4 + q] = __hip_atomic_load(hb + kb * 16 + cc * 4 + q,
                                             __ATOMIC_RELAXED,
                                             __HIP_MEMORY_SCOPE_AGENT);
#pragma unroll
      for (int kb = 0; kb < 16; ++kb) {
        half8 bh, bo;
#pragma unroll
        for (int q = 0; q < 4; ++q) {
          const ull v = hq[kb * 4 + q];
          const unsigned int u0 = (unsigned int)v;
          const unsigned int u1 = (unsigned int)(v >> 32);
          bh[2 * q]     = __builtin_bit_cast(_Float16, (unsigned short)(u0 >> 16));
          bo[2 * q]     = __builtin_bit_cast(_Float16, (unsigned short)(u0 & 0xFFFFu));
          bh[2 * q + 1] = __builtin_bit_cast(_Float16, (unsigned short)(u1 >> 16));
          bo[2 * q + 1] = __builtin_bit_cast(_Float16, (unsigned short)(u1 & 0xFFFFu));
        }
        half8 ah, al;
        rd_w(kb, ah, al);
        aA = __builtin_amdgcn_mfma_f32_16x16x32_f16(ah, bh, aA, 0, 0, 0);
        aB = __builtin_amdgcn_mfma_f32_16x16x32_f16(ah, bo, aB, 0, 0, 0);
        aC = __builtin_amdgcn_mfma_f32_16x16x32_f16(al, bh, aC, 0, 0, 0);
      }
    }
    f32x4 acc;
#pragma unroll
    for (int q = 0; q < 4; ++q) acc[q] = aA[q] + aB[q] + aC[q];
    const float hv = cellp(acc);
    __hip_atomic_store(&g_h[(ot + 1) & 1][bg0 + b_l][j0 + u_l], pack_split(hv),
                       __ATOMIC_RELAXED, __HIP_MEMORY_SCOPE_AGENT);
    // FC partial: sum relu(hv)*wfc over this WG's 8 units per batch row
    float fcv = fmaxf(hv, 0.0f) * wfc;
    fcv += __shfl_xor(fcv, 16);
    fcv += __shfl_xor(fcv, 32);        // sum over the 4 unit-lanes (cc)
    if (lane < 16) aux[wv][lane] = fcv;
    __syncthreads();
    if (tid < 32) {
      const int b = tid;
      g_part[ot][gj][bg0 + b] =
          aux[b >> 4][b & 15] + aux[(b >> 4) + 2][b & 15];
    }
    gbar(++nbar);
  }
}

__global__ void __launch_bounds__(256) k_reduce(const float* __restrict__ b_fc,
                                                float* __restrict__ out) {
  int id = blockIdx.x * 256 + threadIdx.x;
  if (id >= B * OUTL) return;
  int b = id / OUTL, ot = id - b * OUTL;
  float s = b_fc[0];
#pragma unroll 8
  for (int g = 0; g < GJ; ++g) s += g_part[ot][g][b];
  out[id] = s;   // out[b][ot], row-major == id
}

extern "C" void kernel_launch(void* const* d_in, const int* in_sizes, int n_in,
                              void* d_out, int out_size, void* d_ws, size_t ws_size,
                              hipStream_t stream) {
  (void)in_sizes; (void)n_in; (void)d_ws; (void)ws_size; (void)out_size;
  const float* input = (const float*)d_in[0];
  const float* covar = (const float*)d_in[1];
  const float* W_ih1 = (const float*)d_in[2];
  const float* W_hh1 = (const float*)d_in[3];
  const float* b1    = (const float*)d_in[4];
  const float* W_ih2 = (const float*)d_in[5];
  const float* W_hh2 = (const float*)d_in[6];
  const float* b2    = (const float*)d_in[7];
  const float* W_fc  = (const float*)d_in[8];
  const float* b_fc  = (const float*)d_in[9];

  k_init<<<dim3(1), dim3(256), 0, stream>>>();
  k_lstm<<<dim3(NWG), dim3(NT), 0, stream>>>(input, covar, W_ih1, W_hh1, b1,
                                             W_ih2, W_hh2, b2, W_fc);
  k_reduce<<<dim3((B * OUTL + 255) / 256), dim3(256), 0, stream>>>(
      b_fc, (float*)d_out);
}

// Round 7
// 2471.456 us; speedup vs baseline: 2.2480x; 2.2480x over previous
//
#include <hip/hip_runtime.h>

// ---------------------------------------------------------------------------
// multiStepModel: LSTM encoder (T=365) -> relu -> constant-input LSTM decoder
// (90 steps) -> relu -> FC.  Persistent cooperative kernel, 1 WG/CU.
// R7 = R5's coalesced LDS staging of the B operand (h) + R6's reordered gate
// rows (r = unit*4+gate) so each lane's 4 MFMA accumulators are i,f,g,o of
// one (unit,batch) -> LSTM cell in registers (no g_lds round trip, 3 syncs).
// Flag publish via relaxed AGENT-scope store (no RMW serialization); dense
// 64B-coalesced LLC h loads.  Split-f16 3-term MFMA (fp32-class accuracy).
// ---------------------------------------------------------------------------

namespace {
constexpr int B = 128, T = 365, IN = 64, COV = 256, H = 512, OUTL = 90;
constexpr int GB = 4;            // batch groups (independent barrier quorums)
constexpr int GJ = 64;           // hidden groups
constexpr int NWG = GB * GJ;     // 256 workgroups, 1/CU
constexpr int NT = 256;          // threads per WG (4 waves)
constexpr int BS = B / GB;       // 32 batch rows per WG
constexpr int HU = H / GJ;       // 8 hidden units per WG
constexpr int NR = 4 * HU;       // 32 gate rows per WG (reordered unit*4+gate)
constexpr int NSLOT_H = 64;      // 512/8 16B slots (h part of K)
constexpr int NSLOT = 72;        // + 64/8 slots (x part)
}

using ull = unsigned long long;
typedef __attribute__((ext_vector_type(8))) short short8;
typedef __attribute__((ext_vector_type(8))) _Float16 half8;
typedef __attribute__((ext_vector_type(4))) float f32x4;

__device__ unsigned int g_h[2][B][H];      // packed f16 (hi<<16|lo) hidden state
__device__ float g_part[OUTL][GJ][B];      // per-hidden-group FC partials
__device__ int   g_flag[GB][64];           // per-WG monotonic barrier flags

__device__ __forceinline__ float sigf(float x) { return 1.0f / (1.0f + expf(-x)); }

__device__ __forceinline__ float4 fma4(float4 a, float4 b, float4 c) {
  c.x = fmaf(a.x, b.x, c.x); c.y = fmaf(a.y, b.y, c.y);
  c.z = fmaf(a.z, b.z, c.z); c.w = fmaf(a.w, b.w, c.w);
  return c;
}
__device__ __forceinline__ float hsum4(float4 a) { return (a.x + a.y) + (a.z + a.w); }

__device__ __forceinline__ unsigned int pack_split(float v) {
  _Float16 hi = (_Float16)v;
  _Float16 lo = (_Float16)(v - (float)hi);
  return ((unsigned int)__builtin_bit_cast(unsigned short, hi) << 16) |
         (unsigned int)__builtin_bit_cast(unsigned short, lo);
}
__device__ __forceinline__ float unpack_split(unsigned int u) {
  _Float16 hi = __builtin_bit_cast(_Float16, (unsigned short)(u >> 16));
  _Float16 lo = __builtin_bit_cast(_Float16, (unsigned short)(u & 0xFFFFu));
  return (float)hi + (float)lo;
}

__global__ void __launch_bounds__(256) k_init() {
  int t = threadIdx.x;
  if (t < GB * 64) g_flag[t >> 6][t & 63] = 0;
}

__global__ void __launch_bounds__(NT, 1) k_lstm(
    const float* __restrict__ input, const float* __restrict__ covar,
    const float* __restrict__ W_ih1, const float* __restrict__ W_hh1,
    const float* __restrict__ b1,    const float* __restrict__ W_ih2,
    const float* __restrict__ W_hh2, const float* __restrict__ b2,
    const float* __restrict__ W_fc) {
  // Row r = unit*4 + gate (i,f,g,o).  Slot s of row r stored at s ^ (r&7).
  __shared__ __align__(16) short wH[NR][NSLOT * 8];   // W hi   36.9 KB
  __shared__ __align__(16) short wL[NR][NSLOT * 8];   // W lo   36.9 KB
  __shared__ __align__(16) short bH[BS][NSLOT * 8];   // [h;x] hi
  __shared__ __align__(16) short bL[BS][NSLOT * 8];   // [h;x] lo
  __shared__ float pb_lds[NR][33];                    // covproj+b1 / proj2
  __shared__ float aux[4][16];                        // decoder FC combine

  const int tid = threadIdx.x;
  const int gb  = blockIdx.x & (GB - 1);
  const int gj  = blockIdx.x >> 2;
  const int bg0 = gb * BS;
  const int j0  = gj * HU;

  const int lane  = tid & 63;
  const int wv    = tid >> 6;
  const int rows0 = (wv >> 1) * 16;        // gate-row tile (units (wv>>1)*4..+3)
  const int cols0 = (wv & 1) * 16;         // batch tile
  const int ra    = rows0 + (lane & 15);   // A row
  const int b_l   = cols0 + (lane & 15);   // B row == D col == batch
  const int cc    = lane >> 4;             // k-chunk / gate-quad row 0..3
  const int x7    = lane & 7;              // XOR swizzle key (== ra&7 == b_l&7)
  const int u_l   = (wv >> 1) * 4 + cc;    // this lane's unit 0..7

  const int bl = tid >> 3;                 // staging row 0..31
  const int sg = tid & 7;                  // staging phase 0..7
  const int bt = tid & 15;                 // fp32 helper mapping
  const int rt = tid >> 4;

  int nbar = 0;

  // ---- per-gb-group barrier.  Release: __syncthreads (drains vmcnt(0))
  // then ONE plain agent-scope flag store per WG (write-through, no RMW).
  // Poll: lane i watches member i's flag.  No fences anywhere.
  auto gbar = [&](int nb, bool with_x, int tn) {
    __syncthreads();
    if (tid == 0)
      __hip_atomic_store(&g_flag[gb][gj], nb, __ATOMIC_RELAXED,
                         __HIP_MEMORY_SCOPE_AGENT);
    if (with_x) {   // stage x_{tn} into B slots 64..71 during the wait
      const float* src = input + ((size_t)(bg0 + bl) * T + tn) * IN + sg * 8;
      float4 p0 = ((const float4*)src)[0], p1 = ((const float4*)src)[1];
      float f[8] = {p0.x, p0.y, p0.z, p0.w, p1.x, p1.y, p1.z, p1.w};
      short8 hi, lo;
#pragma unroll
      for (int j = 0; j < 8; ++j) {
        _Float16 h_ = (_Float16)f[j];
        hi[j] = __builtin_bit_cast(short, h_);
        lo[j] = __builtin_bit_cast(short, (_Float16)(f[j] - (float)h_));
      }
      const int s2 = (NSLOT_H + sg) ^ (bl & 7);
      *(short8*)&bH[bl][s2 * 8] = hi;
      *(short8*)&bL[bl][s2 * 8] = lo;
    }
    if (tid < 64) {
      while (__hip_atomic_load(&g_flag[gb][tid], __ATOMIC_RELAXED,
                               __HIP_MEMORY_SCOPE_AGENT) < nb)
        __builtin_amdgcn_s_sleep(1);
    }
    __syncthreads();
  };

  // ---- split one 8-float slot into f16 hi/lo W tiles (XOR-swizzled) ----
  auto put_w = [&](int r, int s, const float* src) {
    float4 p0 = ((const float4*)src)[0], p1 = ((const float4*)src)[1];
    float f[8] = {p0.x, p0.y, p0.z, p0.w, p1.x, p1.y, p1.z, p1.w};
    short8 hi, lo;
#pragma unroll
    for (int j = 0; j < 8; ++j) {
      _Float16 h_ = (_Float16)f[j];
      hi[j] = __builtin_bit_cast(short, h_);
      lo[j] = __builtin_bit_cast(short, (_Float16)(f[j] - (float)h_));
    }
    const int s2 = s ^ (r & 7);
    *(short8*)&wH[r][s2 * 8] = hi;
    *(short8*)&wL[r][s2 * 8] = lo;
  };

  // local row r: unit = r>>2, gate = r&3  ->  global W row
  auto wrow = [&](int r) { return (r & 3) * H + j0 + (r >> 2); };

  auto stage_w_hh = [&](const float* Whh) {
    for (int idx = tid; idx < NR * NSLOT_H; idx += NT) {
      const int r = idx >> 6, s = idx & 63;
      put_w(r, s, Whh + (size_t)wrow(r) * H + s * 8);
    }
  };

  // ======================= one-time setup =======================
  stage_w_hh(W_hh1);
  for (int idx = tid; idx < NR * 8; idx += NT) {   // x cols of W_ih1
    const int r = idx >> 3;
    put_w(r, NSLOT_H + (idx & 7),
          W_ih1 + (size_t)wrow(r) * (IN + COV) + (idx & 7) * 8);
  }
  {  // covariate projection + b1 -> pb_lds (fp32, once)
    const int r0 = rt, r1 = rt + 16;
    const int row0 = wrow(r0), row1 = wrow(r1);
    const float4* c0 = (const float4*)(covar + (size_t)(bg0 + bt) * COV);
    const float4* c1 = (const float4*)(covar + (size_t)(bg0 + bt + 16) * COV);
    const float4* w0 = (const float4*)(W_ih1 + (size_t)row0 * (IN + COV) + IN);
    const float4* w1 = (const float4*)(W_ih1 + (size_t)row1 * (IN + COV) + IN);
    float4 a00 = {0, 0, 0, 0}, a01 = a00, a10 = a00, a11 = a00;
    for (int k = 0; k < COV / 4; ++k) {
      float4 va = c0[k], vb = c1[k], wa = w0[k], wb = w1[k];
      a00 = fma4(va, wa, a00); a01 = fma4(va, wb, a01);
      a10 = fma4(vb, wa, a10); a11 = fma4(vb, wb, a11);
    }
    pb_lds[r0][bt]      = hsum4(a00) + b1[row0];
    pb_lds[r1][bt]      = hsum4(a01) + b1[row1];
    pb_lds[r0][bt + 16] = hsum4(a10) + b1[row0];
    pb_lds[r1][bt + 16] = hsum4(a11) + b1[row1];
  }
  {  // stage x_0 into B slots 64..71
    const float* src = input + (size_t)(bg0 + bl) * T * IN + sg * 8;
    float4 p0 = ((const float4*)src)[0], p1 = ((const float4*)src)[1];
    float f[8] = {p0.x, p0.y, p0.z, p0.w, p1.x, p1.y, p1.z, p1.w};
    short8 hi, lo;
#pragma unroll
    for (int j = 0; j < 8; ++j) {
      _Float16 h_ = (_Float16)f[j];
      hi[j] = __builtin_bit_cast(short, h_);
      lo[j] = __builtin_bit_cast(short, (_Float16)(f[j] - (float)h_));
    }
    const int s2 = (NSLOT_H + sg) ^ (bl & 7);
    *(short8*)&bH[bl][s2 * 8] = hi;
    *(short8*)&bL[bl][s2 * 8] = lo;
  }
  __syncthreads();   // wH/wL + pb_lds + x_0 ready

  float pb4[4];
#pragma unroll
  for (int q = 0; q < 4; ++q) pb4[q] = pb_lds[rows0 + cc * 4 + q][b_l];

  float c_state = 0.0f;

  // Stage h (buffer par) -> bH/bL: dense 64B-coalesced LLC loads, then
  // per-word unpack into swizzled slots.
  auto stage_h = [&](int par) {
    ull tmp[32];
    const ull* hr = (const ull*)&g_h[par][bg0 + bl][0];   // 256 ull per row
#pragma unroll
    for (int i = 0; i < 32; ++i)
      tmp[i] = __hip_atomic_load(hr + sg + 8 * i, __ATOMIC_RELAXED,
                                 __HIP_MEMORY_SCOPE_AGENT);
#pragma unroll
    for (int i = 0; i < 32; ++i) {
      const int m = sg + 8 * i;                  // ull index 0..255
      const int s2 = (m >> 2) ^ (bl & 7);        // swizzled 16B slot
      const int p = m & 3;                       // word within slot
      const unsigned u0 = (unsigned)tmp[i], u1 = (unsigned)(tmp[i] >> 32);
      ((unsigned*)&bH[bl][s2 * 8])[p] = (u0 >> 16) | (u1 & 0xFFFF0000u);
      ((unsigned*)&bL[bl][s2 * 8])[p] = (u0 & 0xFFFFu) | (u1 << 16);
    }
  };

  // One MFMA k-block (3-term split product)
  auto mfma_kb = [&](int kb, f32x4& aA, f32x4& aB, f32x4& aC) {
    const int s2 = (kb * 4 + cc) ^ x7;
    const half8 ah = __builtin_bit_cast(half8, *(const short8*)&wH[ra][s2 * 8]);
    const half8 al = __builtin_bit_cast(half8, *(const short8*)&wL[ra][s2 * 8]);
    const half8 bh = __builtin_bit_cast(half8, *(const short8*)&bH[b_l][s2 * 8]);
    const half8 bo = __builtin_bit_cast(half8, *(const short8*)&bL[b_l][s2 * 8]);
    aA = __builtin_amdgcn_mfma_f32_16x16x32_f16(ah, bh, aA, 0, 0, 0);
    aB = __builtin_amdgcn_mfma_f32_16x16x32_f16(ah, bo, aB, 0, 0, 0);
    aC = __builtin_amdgcn_mfma_f32_16x16x32_f16(al, bh, aC, 0, 0, 0);
  };

  // register cell: acc[q] + pb4[q] are the i,f,g,o pre-activations
  auto cellp = [&](const f32x4& acc) -> float {
    const float gi = acc[0] + pb4[0];
    const float gf = acc[1] + pb4[1];
    const float gg = acc[2] + pb4[2];
    const float go = acc[3] + pb4[3];
    c_state = sigf(gf) * c_state + sigf(gi) * tanhf(gg);
    return sigf(go) * tanhf(c_state);
  };

  // =================== encoder: 365 steps ===================
  for (int t = 0; t < T; ++t) {
    if (t > 0) stage_h(t & 1);
    __syncthreads();                           // B tile ready
    f32x4 aA = {0.f, 0.f, 0.f, 0.f}, aB = aA, aC = aA;
#pragma unroll
    for (int kb = 16; kb < 18; ++kb) mfma_kb(kb, aA, aB, aC);   // x part
    if (t > 0) {
#pragma unroll
      for (int kb = 0; kb < 16; ++kb) mfma_kb(kb, aA, aB, aC);  // h part
    }
    f32x4 acc;
#pragma unroll
    for (int q = 0; q < 4; ++q) acc[q] = aA[q] + aB[q] + aC[q];
    float hv = cellp(acc);
    if (t == T - 1) hv = fmaxf(hv, 0.0f);      // relu(h_enc)
    __hip_atomic_store(&g_h[(t + 1) & 1][bg0 + b_l][j0 + u_l], pack_split(hv),
                       __ATOMIC_RELAXED, __HIP_MEMORY_SCOPE_AGENT);
    gbar(++nbar, t + 1 < T, t + 1);            // stage x_{t+1} in the wait
  }

  // ====== transition: proj2 = [relu(h_enc),covar] @ W_ih2^T + b2 (fp32) ======
  {
    const int b0 = bt, b1v = bt + 16;
    const int r0 = rt, r1 = rt + 16;
    const int row0 = wrow(r0), row1 = wrow(r1);
    const float* w0 = W_ih2 + (size_t)row0 * (H + COV);
    const float* w1 = W_ih2 + (size_t)row1 * (H + COV);
    const ull* h0 = (const ull*)&g_h[1][bg0 + b0][0];
    const ull* h1 = (const ull*)&g_h[1][bg0 + b1v][0];
    float a00 = 0.f, a01 = 0.f, a10 = 0.f, a11 = 0.f;
    for (int m = 0; m < H / 2; ++m) {   // h part from packed LLC state
      const ull v0 = __hip_atomic_load(h0 + m, __ATOMIC_RELAXED,
                                       __HIP_MEMORY_SCOPE_AGENT);
      const ull v1 = __hip_atomic_load(h1 + m, __ATOMIC_RELAXED,
                                       __HIP_MEMORY_SCOPE_AGENT);
      const float h00 = unpack_split((unsigned)v0);
      const float h01 = unpack_split((unsigned)(v0 >> 32));
      const float h10 = unpack_split((unsigned)v1);
      const float h11 = unpack_split((unsigned)(v1 >> 32));
      const float wa0 = w0[2 * m], wa1 = w0[2 * m + 1];
      const float wb0 = w1[2 * m], wb1 = w1[2 * m + 1];
      a00 += h00 * wa0 + h01 * wa1;  a01 += h00 * wb0 + h01 * wb1;
      a10 += h10 * wa0 + h11 * wa1;  a11 += h10 * wb0 + h11 * wb1;
    }
    {  // covar part (fp32, cache-hot)
      const float4* c0 = (const float4*)(covar + (size_t)(bg0 + b0) * COV);
      const float4* c1 = (const float4*)(covar + (size_t)(bg0 + b1v) * COV);
      const float4* W0 = (const float4*)w0;
      const float4* W1 = (const float4*)w1;
      float4 s00 = {0, 0, 0, 0}, s01 = s00, s10 = s00, s11 = s00;
      for (int k = 0; k < COV / 4; ++k) {
        float4 ha = c0[k], hb = c1[k], wa = W0[H / 4 + k], wb = W1[H / 4 + k];
        s00 = fma4(ha, wa, s00); s01 = fma4(ha, wb, s01);
        s10 = fma4(hb, wa, s10); s11 = fma4(hb, wb, s11);
      }
      a00 += hsum4(s00); a01 += hsum4(s01);
      a10 += hsum4(s10); a11 += hsum4(s11);
    }
    pb_lds[r0][b0]  = a00 + b2[row0];
    pb_lds[r1][b0]  = a01 + b2[row1];
    pb_lds[r0][b1v] = a10 + b2[row0];
    pb_lds[r1][b1v] = a11 + b2[row1];
  }
  stage_w_hh(W_hh2);        // decoder recurrent weights over encoder ones
  c_state = 0.0f;
  gbar(++nbar, false, 0);   // h_enc reads done; wH/pb_lds published

#pragma unroll
  for (int q = 0; q < 4; ++q) pb4[q] = pb_lds[rows0 + cc * 4 + q][b_l];
  const float wfc = W_fc[j0 + u_l];

  // =================== decoder: 90 steps ===================
  for (int ot = 0; ot < OUTL; ++ot) {
    if (ot > 0) stage_h(ot & 1);
    __syncthreads();
    f32x4 aA = {0.f, 0.f, 0.f, 0.f}, aB = aA, aC = aA;
    if (ot > 0) {
#pragma unroll
      for (int kb = 0; kb < 16; ++kb) mfma_kb(kb, aA, aB, aC);
    }
    f32x4 acc;
#pragma unroll
    for (int q = 0; q < 4; ++q) acc[q] = aA[q] + aB[q] + aC[q];
    const float hv = cellp(acc);
    __hip_atomic_store(&g_h[(ot + 1) & 1][bg0 + b_l][j0 + u_l], pack_split(hv),
                       __ATOMIC_RELAXED, __HIP_MEMORY_SCOPE_AGENT);
    // FC partial: relu(hv)*wfc summed over this WG's 8 units per batch row
    float fcv = fmaxf(hv, 0.0f) * wfc;
    fcv += __shfl_xor(fcv, 16);
    fcv += __shfl_xor(fcv, 32);          // sum over the 4 unit-lanes (cc)
    if (lane < 16) aux[wv][lane] = fcv;
    __syncthreads();
    if (tid < 32) {
      const int b = tid;
      g_part[ot][gj][bg0 + b] = aux[b >> 4][b & 15] + aux[(b >> 4) + 2][b & 15];
    }
    gbar(++nbar, false, 0);
  }
}

__global__ void __launch_bounds__(256) k_reduce(const float* __restrict__ b_fc,
                                                float* __restrict__ out) {
  int id = blockIdx.x * 256 + threadIdx.x;
  if (id >= B * OUTL) return;
  int b = id / OUTL, ot = id - b * OUTL;
  float s = b_fc[0];
#pragma unroll 8
  for (int g = 0; g < GJ; ++g) s += g_part[ot][g][b];
  out[id] = s;   // out[b][ot], row-major == id
}

extern "C" void kernel_launch(void* const* d_in, const int* in_sizes, int n_in,
                              void* d_out, int out_size, void* d_ws, size_t ws_size,
                              hipStream_t stream) {
  (void)in_sizes; (void)n_in; (void)d_ws; (void)ws_size; (void)out_size;
  const float* input = (const float*)d_in[0];
  const float* covar = (const float*)d_in[1];
  const float* W_ih1 = (const float*)d_in[2];
  const float* W_hh1 = (const float*)d_in[3];
  const float* b1    = (const float*)d_in[4];
  const float* W_ih2 = (const float*)d_in[5];
  const float* W_hh2 = (const float*)d_in[6];
  const float* b2    = (const float*)d_in[7];
  const float* W_fc  = (const float*)d_in[8];
  const float* b_fc  = (const float*)d_in[9];

  k_init<<<dim3(1), dim3(256), 0, stream>>>();
  k_lstm<<<dim3(NWG), dim3(NT), 0, stream>>>(input, covar, W_ih1, W_hh1, b1,
                                             W_ih2, W_hh2, b2, W_fc);
  k_reduce<<<dim3((B * OUTL + 255) / 256), dim3(256), 0, stream>>>(
      b_fc, (float*)d_out);
}